// Round 8
// baseline (597.016 us; speedup 1.0000x reference)
//
#include <hip/hip_runtime.h>
#include <hip/hip_bf16.h>

#define BB 8
#define NN 4096
#define EE 131072          // edges per graph
#define ENL (EE + NN)      // + self loops
#define DD 256
#define HH 8
#define HD 2048
#define NPB (BB * NN)      // 32768 nodes total
#define CHUNK 16384        // nodes per y-chunk (4 graphs)
#define CAP 128            // bucket capacity per node (deg max ~58)

typedef __attribute__((ext_vector_type(8))) short bf16x8;
typedef __attribute__((ext_vector_type(4))) float f32x4;
typedef __attribute__((ext_vector_type(2))) unsigned int u32x2;

static __device__ __forceinline__ float bf_lo(unsigned int u) { return __uint_as_float(u << 16); }
static __device__ __forceinline__ float bf_hi(unsigned int u) { return __uint_as_float(u & 0xFFFF0000u); }
static __device__ __forceinline__ unsigned short f2bf(float f) {
    __hip_bfloat16 h = __float2bfloat16(f);
    return *reinterpret_cast<unsigned short*>(&h);
}
static __device__ __forceinline__ unsigned int pack2(float a, float b) {
    return ((unsigned)f2bf(b) << 16) | f2bf(a);
}
static __device__ __forceinline__ void load_lds16(const void* g, void* l) {
    __builtin_amdgcn_global_load_lds(
        (const __attribute__((address_space(1))) unsigned int*)(g),
        (__attribute__((address_space(3))) unsigned int*)(l), 16, 0, 0);
}

// ---------- edge bucketing ----------
__global__ void k_scatter(const int* __restrict__ edges, int* __restrict__ cnt, int* __restrict__ col) {
    int b = blockIdx.y;
    int idx = blockIdx.x * 256 + threadIdx.x;
    if (idx >= ENL) return;
    int src, dst;
    if (idx < EE) { src = edges[b*2*EE + idx]; dst = edges[b*2*EE + EE + idx]; }
    else { src = dst = idx - EE; }
    int g = b * NN + dst;
    int pos = atomicAdd(&cnt[g], 1);
    if (pos < CAP) col[(size_t)g * CAP + pos] = src;
}

// ---------- prep kernel A: M2t (blocks 0..511) + wsatt/wdatt (blocks 512..575) ----------
__global__ __launch_bounds__(256) void k_prepA(const float* __restrict__ W, const float* __restrict__ linW,
                                               unsigned short* __restrict__ M2t,
                                               const float* __restrict__ asrc, const float* __restrict__ adst,
                                               float* __restrict__ wsatt, float* __restrict__ wdatt) {
    __shared__ float red[2][4][64];
    int bx = blockIdx.x;
    if (bx < 512) {
        int cb = bx & 31, h = (bx >> 5) & 7, l = bx >> 8;
        int d = threadIdx.x;
        const float* Bp = W + ((size_t)l * HD + h * DD) * DD;
        const float* Ap = linW + ((size_t)l * DD + cb * 8) * HD + h * DD;
        float acc[8] = {};
        for (int o = 0; o < DD; ++o) {
            float w = Bp[(size_t)o * DD + d];
            #pragma unroll
            for (int c = 0; c < 8; ++c)
                acc[c] = fmaf(Ap[(size_t)c * HD + o], w, acc[c]);
        }
        #pragma unroll
        for (int c = 0; c < 8; ++c)
            M2t[((size_t)l * DD + cb * 8 + c) * HD + h * DD + d] = f2bf(acc[c]);
    } else {
        int idx = bx - 512;
        int kb = idx & 3, h = (idx >> 2) & 7, l = idx >> 5;
        int k = threadIdx.x & 63, dg = threadIdx.x >> 6;
        float accs = 0.f, accd = 0.f;
        #pragma unroll 4
        for (int dd = 0; dd < 64; ++dd) {
            int d = dg * 64 + dd;
            float w = W[((size_t)l * HD + h * DD + d) * DD + kb * 64 + k];
            accs = fmaf(asrc[(l*HH + h)*DD + d], w, accs);
            accd = fmaf(adst[(l*HH + h)*DD + d], w, accd);
        }
        red[0][dg][k] = accs; red[1][dg][k] = accd;
        __syncthreads();
        int t = threadIdx.x;
        if (t < 64)
            wsatt[(l*HH + h)*DD + kb*64 + t] = red[0][0][t] + red[0][1][t] + red[0][2][t] + red[0][3][t];
        else if (t < 128) {
            int kk = t - 64;
            wdatt[(l*HH + h)*DD + kb*64 + kk] = red[1][0][kk] + red[1][1][kk] + red[1][2][kk] + red[1][3][kk];
        }
    }
}

// ---------- prep kernel B: bias2 (blocks 0..127) + attfrag pack (blocks 128..131) ----------
__global__ __launch_bounds__(256) void k_prepB(const float* __restrict__ gbias, const float* __restrict__ linW,
                                               const float* __restrict__ linb, float* __restrict__ bias2,
                                               const float* __restrict__ ws, const float* __restrict__ wd,
                                               unsigned short* __restrict__ frag) {
    int bx = blockIdx.x;
    if (bx < 128) {
        int wv = threadIdx.x >> 6, lane = threadIdx.x & 63;
        int o = bx * 4 + wv;
        int l = o >> 8, c = o & 255;
        const float4* g4 = (const float4*)(gbias + l * HD);
        const float4* w4 = (const float4*)(linW + (size_t)l * DD * HD + (size_t)c * HD);
        float acc = 0.f;
        #pragma unroll
        for (int j = 0; j < 8; ++j) {
            float4 g = g4[j * 64 + lane]; float4 w = w4[j * 64 + lane];
            acc += g.x * w.x + g.y * w.y + g.z * w.z + g.w * w.w;
        }
        #pragma unroll
        for (int msk = 1; msk < 64; msk <<= 1) acc += __shfl_xor(acc, msk);
        if (lane == 0) bias2[o] = acc + linb[o];
    } else {
        int idx = bx - 128;
        int l = idx >> 1;
        int t = (idx & 1) * 256 + threadIdx.x;
        int ks = t >> 6, lane = t & 63, c = lane & 15, q = lane >> 4;
        #pragma unroll
        for (int j = 0; j < 8; ++j) {
            int k = ks * 32 + q * 8 + j;
            float v = (c < 8) ? ws[(l*HH + c)*DD + k] : wd[(l*HH + (c-8))*DD + k];
            frag[((size_t)l * 512 + t) * 8 + j] = f2bf(v);
        }
    }
}

// ---------- f32 -> bf16 row conversion ----------
__global__ void k_tobf(const float* __restrict__ X, uint2* __restrict__ xb2) {
    int idx = blockIdx.x * 256 + threadIdx.x;
    float4 v = *(const float4*)(X + (size_t)idx * 4);
    uint2 o; o.x = pack2(v.x, v.y); o.y = pack2(v.z, v.w);
    xb2[idx] = o;
}

// ---------- attention scores via MFMA: [N x 256] @ [256 x 16] ----------
__global__ __launch_bounds__(256) void k_attn_mfma(const unsigned short* __restrict__ xb,
                                                   const unsigned short* __restrict__ attfrag,
                                                   float* __restrict__ a_s, float* __restrict__ a_d) {
    int tid = threadIdx.x;
    int wv = tid >> 6, lane = tid & 63;
    int m0 = blockIdx.x * 64 + wv * 16;
    int c = lane & 15, q = lane >> 4;
    const unsigned short* arow = xb + (size_t)(m0 + c) * DD;
    f32x4 acc = (f32x4){0.f, 0.f, 0.f, 0.f};
    #pragma unroll
    for (int ks = 0; ks < 8; ++ks) {
        bf16x8 af = *(const bf16x8*)(arow + ks * 32 + q * 8);
        bf16x8 bf = *(const bf16x8*)(attfrag + (size_t)(ks * 64 + lane) * 8);
        acc = __builtin_amdgcn_mfma_f32_16x16x32_bf16(af, bf, acc, 0, 0, 0);
    }
    #pragma unroll
    for (int rg = 0; rg < 4; ++rg) {
        int row = m0 + q * 4 + rg;
        if (c < 8) a_s[row * 8 + c] = acc[rg];
        else       a_d[row * 8 + (c - 8)] = acc[rg];
    }
}

// ---------- MFMA aggregation: y[n,h,:] = (1/sum w) * sum_e w[e,h] x[src_e,:] ----------
// Per wave: one dst node. A = weights [16h x 32e] (bf16, built in-reg),
// B = gathered x rows [32e x 16c] staged to wave-private LDS subtiled for ds_read_b64_tr_b16.
// tr-read vaddr is LINEAR per-lane (base + 8*lane); the HW transpose delivers
// lane l elem j <- lds element (l&15) + 16j + (l>>4)*64 (m156). r7 bug: vaddr had the
// permutation baked in (double-applied). Staging source bijection verified symbolically.
__global__ __launch_bounds__(256) void k_agg_mfma(const int* __restrict__ cnt, const int* __restrict__ col,
                                                  const float* __restrict__ a_s, const float* __restrict__ a_d,
                                                  const uint2* __restrict__ xb2, uint2* __restrict__ y2,
                                                  int node0) {
    __shared__ char lds[33792];          // 4 waves x 8448
    int wave = threadIdx.x >> 6, lane = threadIdx.x & 63;
    char* wb = lds + wave * 8448;
    unsigned wboff = (unsigned)(size_t)(__attribute__((address_space(3))) char*)wb;

    int blk = blockIdx.x;
    int xcd = blk & 7, q = blk >> 3;
    int gl = xcd >> 1;
    int sub = ((xcd & 1) << 9) | q;
    int g = node0 + gl * NN + sub * 4 + wave;
    int b = g >> 12, gb = b * NN;
    int re = cnt[g];
    const int* cl = col + (size_t)g * CAP;

    // per-lane constants for staging: s' = lane>>3, e_sub = interleave tab {0,2,4,6,1,3,5,7}
    int sp = lane >> 3;
    int e_sub = ((sp & 3) << 1) | (sp >> 2);
    int e_lane = e_sub * 4 + ((lane & 7) >> 1);
    int chalf = (lane & 1) * 16;          // byte offset within 32B channel-pair span
    int hh = lane & 7;
    float adh = a_d[(size_t)g * 8 + hh];
    const char* xbase = (const char*)xb2;

    // tr-read base: LINEAR per-lane addressing (HW applies the transpose permute)
    unsigned vbase = wboff + lane * 8;

    f32x4 acc[16];
    #pragma unroll
    for (int t = 0; t < 16; ++t) acc[t] = (f32x4){0.f, 0.f, 0.f, 0.f};
    float sacc = 0.f;

    for (int c0 = 0; c0 < re; c0 += 32) {
        // edge row for staging (clamped: padded edges read a valid finite row, killed by w=0)
        int se = c0 + e_lane; if (se > re - 1) se = re - 1;
        int r = cl[se];
        const char* src = xbase + ((size_t)(gb + r)) * 512 + chalf;
        // stage half0: channel tiles 0..7
        #pragma unroll
        for (int i = 0; i < 8; ++i)
            load_lds16(src + i * 32, wb + i * 1024);

        // weights A-frag: lane holds w[k = (lane>>4)*8+j][head = lane&15 (dup &7)]
        int kb = c0 + ((lane >> 4) << 3);
        float w[8];
        #pragma unroll
        for (int j = 0; j < 8; ++j) {
            int e = kb + j;
            int ei = e; if (ei > re - 1) ei = re - 1;
            int s = cl[ei];
            float xs = a_s[(size_t)(gb + s) * 8 + hh] + adh;
            xs = (xs > 0.f) ? xs : 0.2f * xs;
            float ww = (e < re) ? __expf(xs) : 0.f;
            w[j] = ww;
            sacc += ww;
        }
        union AU { unsigned u[4]; bf16x8 v; } au;
        au.u[0] = pack2(w[0], w[1]); au.u[1] = pack2(w[2], w[3]);
        au.u[2] = pack2(w[4], w[5]); au.u[3] = pack2(w[6], w[7]);
        bf16x8 af = au.v;

        asm volatile("s_waitcnt vmcnt(0)" ::: "memory");
        __builtin_amdgcn_sched_barrier(0);
        #pragma unroll
        for (int t = 0; t < 8; ++t) {
            u32x2 r1, r2;
            unsigned vat = vbase + t * 1024;
            asm volatile("ds_read_b64_tr_b16 %0, %2\n\t"
                         "ds_read_b64_tr_b16 %1, %2 offset:512"
                         : "=&v"(r1), "=&v"(r2) : "v"(vat));
            asm volatile("s_waitcnt lgkmcnt(0)" ::: "memory");
            __builtin_amdgcn_sched_barrier(0);
            union BU { struct { u32x2 a, b; } p; bf16x8 v; } bu;
            bu.p.a = r1; bu.p.b = r2;
            acc[t] = __builtin_amdgcn_mfma_f32_16x16x32_bf16(af, bu.v, acc[t], 0, 0, 0);
        }
        // stage half1: channel tiles 8..15 (lgkm drained -> safe to overwrite)
        #pragma unroll
        for (int i = 0; i < 8; ++i)
            load_lds16(src + (8 + i) * 32, wb + i * 1024);
        asm volatile("s_waitcnt vmcnt(0)" ::: "memory");
        __builtin_amdgcn_sched_barrier(0);
        #pragma unroll
        for (int t = 0; t < 8; ++t) {
            u32x2 r1, r2;
            unsigned vat = vbase + t * 1024;
            asm volatile("ds_read_b64_tr_b16 %0, %2\n\t"
                         "ds_read_b64_tr_b16 %1, %2 offset:512"
                         : "=&v"(r1), "=&v"(r2) : "v"(vat));
            asm volatile("s_waitcnt lgkmcnt(0)" ::: "memory");
            __builtin_amdgcn_sched_barrier(0);
            union BU { struct { u32x2 a, b; } p; bf16x8 v; } bu;
            bu.p.a = r1; bu.p.b = r2;
            acc[8 + t] = __builtin_amdgcn_mfma_f32_16x16x32_bf16(af, bu.v, acc[8 + t], 0, 0, 0);
        }
    }

    // denominators: head (lane&15) total = sum over k-groups (lanes ^16, ^32)
    sacc += __shfl_xor(sacc, 16);
    sacc += __shfl_xor(sacc, 32);
    float rinv = 1.f / (sacc + 1e-16f);
    float rv[4];
    #pragma unroll
    for (int rg = 0; rg < 4; ++rg)
        rv[rg] = __shfl(rinv, ((lane >> 4) & 1) * 4 + rg);   // row = (lane>>4)*4+rg for lane<32

    // normalize + transpose through LDS f32 [8][260]
    float* fb = (float*)wb;
    if (lane < 32) {
        int rbase = (lane >> 4) * 4;
        #pragma unroll
        for (int t = 0; t < 16; ++t) {
            #pragma unroll
            for (int rg = 0; rg < 4; ++rg)
                fb[(rbase + rg) * 260 + t * 16 + (lane & 15)] = acc[t][rg] * rv[rg];
        }
    }
    // wave-local: compiler inserts lgkmcnt between ds_write and ds_read
    int h = lane >> 3, m = lane & 7;
    const float* rowp = fb + h * 260;
    char* yrow = (char*)y2 + ((size_t)(g - node0)) * 4096 + h * 512;
    #pragma unroll
    for (int k = 0; k < 8; ++k) {
        float4 v = *(const float4*)(rowp + m * 4 + k * 32);
        uint2 o; o.x = pack2(v.x, v.y); o.y = pack2(v.z, v.w);
        *(uint2*)(yrow + m * 8 + k * 64) = o;
    }
}

// ---------- fused: y @ M2t^T (MFMA, double-buffered) -> +bias -> LN -> +res -> relu ----------
// tile 64(M) x 256(N), BK=64, 512 threads (8 waves, each 64M x 32N), 2-phase pipeline
__global__ __launch_bounds__(512) void k_gemm_ln(const unsigned short* __restrict__ Yb,
                                                 const unsigned short* __restrict__ Bt,
                                                 const float* __restrict__ bias2,
                                                 const float* __restrict__ gamma,
                                                 const float* __restrict__ beta,
                                                 const float* __restrict__ res,
                                                 float* __restrict__ out,
                                                 unsigned int* __restrict__ xb,
                                                 int node0) {
    __shared__ char lds[86528];
    int tid = threadIdx.x;
    int wv = tid >> 6, lane = tid & 63;
    int m0 = blockIdx.x * 64;
    int c = lane & 15, q = lane >> 4;
    f32x4 acc[4][2];
    #pragma unroll
    for (int mf = 0; mf < 4; ++mf)
        #pragma unroll
        for (int nf = 0; nf < 2; ++nf) acc[mf][nf] = (f32x4){0.f, 0.f, 0.f, 0.f};

    #define STAGE(BUF, KT) do {                                                        \
        int row_ = tid >> 3, j_ = tid & 7, jp_ = j_ ^ (row_ & 7);                      \
        load_lds16(Yb + (size_t)(m0 + row_) * HD + (KT) + jp_ * 8,                     \
                   lds + (BUF) * 40960 + wv * 1024);                                   \
        _Pragma("unroll")                                                              \
        for (int it_ = 0; it_ < 4; ++it_) {                                            \
            int ci_ = it_ * 512 + tid;                                                 \
            int br_ = ci_ >> 3, bj_ = ci_ & 7, bjp_ = bj_ ^ (br_ & 7);                 \
            load_lds16(Bt + (size_t)br_ * HD + (KT) + bjp_ * 8,                        \
                       lds + (BUF) * 40960 + 8192 + it_ * 8192 + wv * 1024);           \
        }                                                                              \
    } while (0)

    #define COMPUTE(BUF) do {                                                          \
        const char* Ab_ = lds + (BUF) * 40960;                                         \
        const char* Bb_ = lds + (BUF) * 40960 + 8192;                                  \
        _Pragma("unroll")                                                              \
        for (int ks = 0; ks < 2; ++ks) {                                               \
            int kb = ks * 64 + (q << 4);                                               \
            bf16x8 af[4], bfr[2];                                                      \
            _Pragma("unroll")                                                          \
            for (int mf = 0; mf < 4; ++mf) {                                           \
                int r = mf * 16 + c;                                                   \
                af[mf] = *(const bf16x8*)(Ab_ + r * 128 + (kb ^ ((r & 7) << 4)));      \
            }                                                                          \
            _Pragma("unroll")                                                          \
            for (int nf = 0; nf < 2; ++nf) {                                           \
                int nr = wv * 32 + nf * 16 + c;                                        \
                bfr[nf] = *(const bf16x8*)(Bb_ + nr * 128 + (kb ^ ((nr & 7) << 4)));   \
            }                                                                          \
            _Pragma("unroll")                                                          \
            for (int mf = 0; mf < 4; ++mf)                                             \
                _Pragma("unroll")                                                      \
                for (int nf = 0; nf < 2; ++nf)                                         \
                    acc[mf][nf] = __builtin_amdgcn_mfma_f32_16x16x32_bf16(             \
                        af[mf], bfr[nf], acc[mf][nf], 0, 0, 0);                        \
        }                                                                              \
    } while (0)

    STAGE(0, 0);
    __syncthreads();
    for (int t = 0; t < 32; t += 2) {
        if (t + 1 < 32) STAGE(1, (t + 1) * 64);
        COMPUTE(0);
        __syncthreads();
        if (t + 2 < 32) STAGE(0, (t + 2) * 64);
        COMPUTE(1);
        __syncthreads();
    }
    #undef STAGE
    #undef COMPUTE

    float2* lnbuf = (float2*)(lds + 81920);
    float2* musd  = (float2*)(lds + 86016);
    float b2[2], gmv[2], btv[2];
    #pragma unroll
    for (int nf = 0; nf < 2; ++nf) {
        int colx = wv * 32 + nf * 16 + c;
        b2[nf] = bias2[colx]; gmv[nf] = gamma[colx]; btv[nf] = beta[colx];
    }
    #pragma unroll
    for (int mf = 0; mf < 4; ++mf)
        #pragma unroll
        for (int nf = 0; nf < 2; ++nf)
            #pragma unroll
            for (int rg = 0; rg < 4; ++rg)
                acc[mf][nf][rg] += b2[nf];
    #pragma unroll
    for (int mf = 0; mf < 4; ++mf) {
        #pragma unroll
        for (int rg = 0; rg < 4; ++rg) {
            float s = 0.f, ss = 0.f;
            #pragma unroll
            for (int nf = 0; nf < 2; ++nf) { float v = acc[mf][nf][rg]; s += v; ss += v * v; }
            #pragma unroll
            for (int msk = 1; msk < 16; msk <<= 1) { s += __shfl_xor(s, msk); ss += __shfl_xor(ss, msk); }
            if (c == 0) lnbuf[(mf * 16 + q * 4 + rg) * 8 + wv] = make_float2(s, ss);
        }
    }
    __syncthreads();
    if (tid < 64) {
        float s = 0.f, ss = 0.f;
        #pragma unroll
        for (int w = 0; w < 8; ++w) { float2 p = lnbuf[tid * 8 + w]; s += p.x; ss += p.y; }
        float mu = s * (1.f / 256.f);
        float var = ss * (1.f / 256.f) - mu * mu;
        musd[tid] = make_float2(mu, rsqrtf(var + 1e-5f));
    }
    __syncthreads();
    #pragma unroll
    for (int mf = 0; mf < 4; ++mf) {
        #pragma unroll
        for (int rg = 0; rg < 4; ++rg) {
            int row = mf * 16 + q * 4 + rg;
            float2 ms = musd[row];
            size_t grow = (size_t)(node0 + m0 + row);
            #pragma unroll
            for (int nf = 0; nf < 2; ++nf) {
                int colx = wv * 32 + nf * 16 + c;
                float o = (acc[mf][nf][rg] - ms.x) * ms.y * gmv[nf] + btv[nf] + res[grow * DD + colx];
                o = fmaxf(o, 0.f);
                out[grow * DD + colx] = o;
                float nb = __shfl_xor(o, 1);
                if (!(c & 1)) xb[grow * 128 + (colx >> 1)] = pack2(o, nb);
            }
        }
    }
}

extern "C" void kernel_launch(void* const* d_in, const int* in_sizes, int n_in,
                              void* d_out, int out_size, void* d_ws, size_t ws_size,
                              hipStream_t stream) {
    const float* emb   = (const float*)d_in[0];
    const int*   edges = (const int*)d_in[1];
    const float* W     = (const float*)d_in[2];
    const float* asrc  = (const float*)d_in[3];
    const float* adst  = (const float*)d_in[4];
    const float* gbias = (const float*)d_in[5];
    const float* linW  = (const float*)d_in[6];
    const float* linb  = (const float*)d_in[7];
    const float* gam   = (const float*)d_in[8];
    const float* bet   = (const float*)d_in[9];
    float* out = (float*)d_out;

    // workspace layout (bytes), total ~105 MB
    char* ws = (char*)d_ws;
    uint2*          y2      = (uint2*)(ws + 0);                  // 67108864 (CHUNK x 2048 bf16)
    uint2*          xb2     = (uint2*)(ws + 67108864);           // 16777216 (NPB x 256 bf16)
    unsigned short* M2t     = (unsigned short*)(ws + 83886080);  // 2097152
    float*          wsatt   = (float*)(ws + 85983232);           // 16384
    float*          wdatt   = (float*)(ws + 85999616);           // 16384
    float*          bias2   = (float*)(ws + 86016000);           // 2048
    float*          a_s     = (float*)(ws + 86018048);           // 1048576
    float*          a_d     = (float*)(ws + 87066624);           // 1048576
    int*            cnt     = (int*)(ws + 88115200);             // 131072
    int*            colx    = (int*)(ws + 88246272);             // 16777216 (NPB x CAP)
    unsigned short* attfrag = (unsigned short*)(ws + 105023488); // 16384

    hipMemsetAsync(cnt, 0, NPB * sizeof(int), stream);
    k_scatter<<<dim3((ENL + 255) / 256, BB), 256, 0, stream>>>(edges, cnt, colx);
    k_prepA<<<dim3(576), 256, 0, stream>>>(W, linW, M2t, asrc, adst, wsatt, wdatt);
    k_prepB<<<dim3(132), 256, 0, stream>>>(gbias, linW, linb, bias2, wsatt, wdatt, attfrag);
    k_tobf<<<dim3(NPB * 64 / 256), 256, 0, stream>>>(emb, xb2);

    for (int l = 0; l < 2; ++l) {
        const float* X = (l == 0) ? emb : out;
        k_attn_mfma<<<dim3(NPB / 64), 256, 0, stream>>>((const unsigned short*)xb2,
                                                        attfrag + (size_t)l * 4096, a_s, a_d);
        for (int cc = 0; cc < 2; ++cc) {
            int node0 = cc * CHUNK;
            k_agg_mfma<<<dim3(CHUNK / 4), 256, 0, stream>>>(cnt, colx, a_s, a_d, xb2, y2, node0);
            k_gemm_ln<<<dim3(CHUNK / 64), 512, 0, stream>>>((const unsigned short*)y2,
                                                            M2t + (size_t)l * DD * HD, bias2 + l * DD,
                                                            gam, bet, X, out,
                                                            (unsigned int*)xb2, node0);
        }
    }
}